// Round 3
// baseline (313.672 us; speedup 1.0000x reference)
//
#include <hip/hip_runtime.h>

typedef unsigned int uint;
typedef unsigned long long u64;
typedef float f32x4 __attribute__((ext_vector_type(4)));
typedef float f32x2 __attribute__((ext_vector_type(2)));

#define TD 20000
// ws layout in float units:
//  H:      [200][12][4]  = 9600 floats  (FIR taps: {e_s, i_s, e_ns, i_ns} per (k,s))
//  SPREAD: 5000 uints, SoA uint4 arrays of 5-bit-field spread masks:
//          Ea[500] | Eb[500] | Ia[125] | Ib[125]  (uint4 units)
//  IN:     [20000][24]   (e counts in 0..11, i counts in 12..23)
//  SYN:    [20000][24]   (syn_s in 0..11, syn_ns in 12..23)
#define WS_H      0
#define WS_SPREAD 9600
#define WS_IN     14600
#define WS_SYN    494600

__device__ __forceinline__ float sigf(float x) { return 1.f / (1.f + __expf(-x)); }

// ---------------- K1: FIR kernels + spread connectivity masks (SoA) ----------------
__global__ __launch_bounds__(256) void k1_precomp(
    const float* __restrict__ Ce, const float* __restrict__ Ci,
    const float* __restrict__ Wsy_s, const float* __restrict__ Wsy_ns,
    const float* __restrict__ Del_s, const float* __restrict__ Del_ns,
    float* __restrict__ ws) {
  int p = blockIdx.x * 256 + threadIdx.x;
  if (p < 2400) {
    int k = p / 12, s = p - (p / 12) * 12;
    float o[4];
    for (int ch = 0; ch < 2; ++ch) {
      const float* W = ch ? Wsy_ns : Wsy_s;
      const float* D = ch ? Del_ns : Del_s;
      for (int c = 0; c < 2; ++c) {
        float ts = fmaxf((float)k - __expf(D[s * 2 + c]), 0.f);
        float v = 0.f;
        for (int b = 0; b < 3; ++b) {
          float tt = ts * __expf(-0.5f * (float)b);
          v += W[s * 6 + b * 2 + c] * tt * __expf(-tt);
        }
        o[ch * 2 + c] = v;
      }
    }
    float* H = ws + WS_H + (size_t)(k * 12 + s) * 4;
    H[0] = o[0]; H[1] = o[1]; H[2] = o[2]; H[3] = o[3];
  }
  int q = p - 2400;
  if (q >= 0 && q < 2500) {
    uint m = 0;
    if (q < 2000) {
      for (int s = 0; s < 12; ++s) m |= (Ce[s * 2000 + q] != 0.f ? (1u << s) : 0u);
    } else {
      int e = q - 2000;
      for (int s = 0; s < 12; ++s) m |= (Ci[s * 500 + e] != 0.f ? (1u << s) : 0u);
    }
    u64 sp = 0ull;
    for (int s = 0; s < 12; ++s) sp |= (u64)((m >> s) & 1u) << (5 * s);
    uint lo = (uint)sp, hi = (uint)(sp >> 32);
    uint* U = (uint*)(ws + WS_SPREAD);
    int base, idx;
    if (q < 2000) {
      int g4 = q >> 2, r = q & 3;
      base = (r < 2) ? 0 : 2000;          // Ea : Eb
      idx = g4 * 4 + 2 * (r & 1);
    } else {
      int e = q - 2000;
      int g4 = e >> 2, r = e & 3;
      base = (r < 2) ? 4000 : 4500;       // Ia : Ib
      idx = g4 * 4 + 2 * (r & 1);
    }
    U[base + idx] = lo;
    U[base + idx + 1] = hi;
  }
}

// ---------------- K2: IN = S @ C^T via spread-mask accumulation ----------------
// 2 time-rows per wave; masks read directly from global (L1-resident 20 KB,
// SoA layout -> 16B lane stride, fully coalesced, no LDS, no syncthreads).
// Memory-floor bound: 200 MB spike reads ~= 30 us.
__global__ __launch_bounds__(256) void k2_project(
    const float* __restrict__ Se, const float* __restrict__ Si,
    float* __restrict__ ws) {
  const int lane = threadIdx.x & 63;
  const int w = blockIdx.x * 4 + (threadIdx.x >> 6);  // row pair 0..9999
  const size_t t0 = (size_t)w * 2;
  const uint4* U4 = (const uint4*)(ws + WS_SPREAD);
  float* INb = ws + WS_IN;

  uint e0[12], e1[12];
#pragma unroll
  for (int s = 0; s < 12; ++s) { e0[s] = 0u; e1[s] = 0u; }
  u64 a0 = 0ull, a1 = 0ull;
  const f32x4* S0 = (const f32x4*)(Se + t0 * 2000);
  const f32x4* S1 = S0 + 500;
#pragma unroll
  for (int it = 0; it < 8; ++it) {
    int i4 = lane + it * 64;
    if (i4 < 500) {
      uint4 a = U4[i4];
      uint4 b = U4[500 + i4];
      u64 m0 = (u64)a.x | ((u64)a.y << 32);
      u64 m1 = (u64)a.z | ((u64)a.w << 32);
      u64 m2 = (u64)b.x | ((u64)b.y << 32);
      u64 m3 = (u64)b.z | ((u64)b.w << 32);
      f32x4 v0 = __builtin_nontemporal_load(&S0[i4]);
      f32x4 v1 = __builtin_nontemporal_load(&S1[i4]);
      a0 += (v0.x != 0.f ? m0 : 0ull); a1 += (v1.x != 0.f ? m0 : 0ull);
      a0 += (v0.y != 0.f ? m1 : 0ull); a1 += (v1.y != 0.f ? m1 : 0ull);
      a0 += (v0.z != 0.f ? m2 : 0ull); a1 += (v1.z != 0.f ? m2 : 0ull);
      a0 += (v0.w != 0.f ? m3 : 0ull); a1 += (v1.w != 0.f ? m3 : 0ull);
    }
    if (it == 3) {
#pragma unroll
      for (int s = 0; s < 12; ++s) {
        e0[s] += (uint)(a0 >> (5 * s)) & 31u;
        e1[s] += (uint)(a1 >> (5 * s)) & 31u;
      }
      a0 = 0ull; a1 = 0ull;
    }
  }
#pragma unroll
  for (int s = 0; s < 12; ++s) {
    e0[s] += (uint)(a0 >> (5 * s)) & 31u;
    e1[s] += (uint)(a1 >> (5 * s)) & 31u;
  }
  // ----- I channel (max 8 per field, no flush needed) -----
  u64 ai0 = 0ull, ai1 = 0ull;
  const f32x4* T0 = (const f32x4*)(Si + t0 * 500);
  const f32x4* T1 = T0 + 125;
#pragma unroll
  for (int it = 0; it < 2; ++it) {
    int i4 = lane + it * 64;
    if (i4 < 125) {
      uint4 a = U4[1000 + i4];
      uint4 b = U4[1125 + i4];
      u64 m0 = (u64)a.x | ((u64)a.y << 32);
      u64 m1 = (u64)a.z | ((u64)a.w << 32);
      u64 m2 = (u64)b.x | ((u64)b.y << 32);
      u64 m3 = (u64)b.z | ((u64)b.w << 32);
      f32x4 v0 = __builtin_nontemporal_load(&T0[i4]);
      f32x4 v1 = __builtin_nontemporal_load(&T1[i4]);
      ai0 += (v0.x != 0.f ? m0 : 0ull); ai1 += (v1.x != 0.f ? m0 : 0ull);
      ai0 += (v0.y != 0.f ? m1 : 0ull); ai1 += (v1.y != 0.f ? m1 : 0ull);
      ai0 += (v0.z != 0.f ? m2 : 0ull); ai1 += (v1.z != 0.f ? m2 : 0ull);
      ai0 += (v0.w != 0.f ? m3 : 0ull); ai1 += (v1.w != 0.f ? m3 : 0ull);
    }
  }
  uint p0[12], p1[12];
#pragma unroll
  for (int s = 0; s < 12; ++s) {
    p0[s] = e0[s] | (((uint)(ai0 >> (5 * s)) & 31u) << 16);
    p1[s] = e1[s] | (((uint)(ai1 >> (5 * s)) & 31u) << 16);
  }
#pragma unroll
  for (int s = 0; s < 12; ++s) {
    uint v = p0[s];
    v += __shfl_xor(v, 32, 64); v += __shfl_xor(v, 16, 64);
    v += __shfl_xor(v, 8, 64);  v += __shfl_xor(v, 4, 64);
    v += __shfl_xor(v, 2, 64);  v += __shfl_xor(v, 1, 64);
    p0[s] = v;
    uint u = p1[s];
    u += __shfl_xor(u, 32, 64); u += __shfl_xor(u, 16, 64);
    u += __shfl_xor(u, 8, 64);  u += __shfl_xor(u, 4, 64);
    u += __shfl_xor(u, 2, 64);  u += __shfl_xor(u, 1, 64);
    p1[s] = u;
  }
  if (lane == 0) {
    float4* o = (float4*)(INb + t0 * 24);
    o[0] = make_float4((float)(p0[0] & 0xffffu), (float)(p0[1] & 0xffffu),
                       (float)(p0[2] & 0xffffu), (float)(p0[3] & 0xffffu));
    o[1] = make_float4((float)(p0[4] & 0xffffu), (float)(p0[5] & 0xffffu),
                       (float)(p0[6] & 0xffffu), (float)(p0[7] & 0xffffu));
    o[2] = make_float4((float)(p0[8] & 0xffffu), (float)(p0[9] & 0xffffu),
                       (float)(p0[10] & 0xffffu), (float)(p0[11] & 0xffffu));
    o[3] = make_float4((float)(p0[0] >> 16), (float)(p0[1] >> 16),
                       (float)(p0[2] >> 16), (float)(p0[3] >> 16));
    o[4] = make_float4((float)(p0[4] >> 16), (float)(p0[5] >> 16),
                       (float)(p0[6] >> 16), (float)(p0[7] >> 16));
    o[5] = make_float4((float)(p0[8] >> 16), (float)(p0[9] >> 16),
                       (float)(p0[10] >> 16), (float)(p0[11] >> 16));
  }
  if (lane == 1) {
    float4* o = (float4*)(INb + (t0 + 1) * 24);
    o[0] = make_float4((float)(p1[0] & 0xffffu), (float)(p1[1] & 0xffffu),
                       (float)(p1[2] & 0xffffu), (float)(p1[3] & 0xffffu));
    o[1] = make_float4((float)(p1[4] & 0xffffu), (float)(p1[5] & 0xffffu),
                       (float)(p1[6] & 0xffffu), (float)(p1[7] & 0xffffu));
    o[2] = make_float4((float)(p1[8] & 0xffffu), (float)(p1[9] & 0xffffu),
                       (float)(p1[10] & 0xffffu), (float)(p1[11] & 0xffffu));
    o[3] = make_float4((float)(p1[0] >> 16), (float)(p1[1] >> 16),
                       (float)(p1[2] >> 16), (float)(p1[3] >> 16));
    o[4] = make_float4((float)(p1[4] >> 16), (float)(p1[5] >> 16),
                       (float)(p1[6] >> 16), (float)(p1[7] >> 16));
    o[5] = make_float4((float)(p1[8] >> 16), (float)(p1[9] >> 16),
                       (float)(p1[10] >> 16), (float)(p1[11] >> 16));
  }
}

// ---------------- K3: causal FIR, K=200, s-group split across blockIdx.y ----------------
// block = 64 t's x 3 subunits (both channels); 4 waves split the 200 taps.
// LDS tile interleaved as float2 {e,i} per (s,row): one tap's pair = a single
// 8B-aligned ds_read_b64 (addr (s*264+rb)*8 always 8B-aligned) -> DS issues
// halved (12 b32 -> 6 b64 per kk). red[] row stride 7 (gcd(7,32)=1, no conflict).
// Tap index wave-uniform via readfirstlane so tap loads go scalar (s_load).
__global__ __launch_bounds__(256) void k3_conv(float* __restrict__ ws) {
  __shared__ f32x2 tile2[3 * 264];
  __shared__ float red[4 * 64 * 7];
  const int g = blockIdx.y;        // subunit group: s in [3g, 3g+3)
  const int t0 = blockIdx.x * 64;
  const float* INb = ws + WS_IN;
  for (int p = threadIdx.x; p < 263 * 3; p += 256) {
    int row = p / 3, c = p - row * 3;
    int gt = t0 - 199 + row;
    float ev = 0.f, iv = 0.f;
    if (gt >= 0 && gt < TD) {
      ev = INb[(size_t)gt * 24 + 3 * g + c];
      iv = INb[(size_t)gt * 24 + 12 + 3 * g + c];
    }
    f32x2 pr; pr.x = ev; pr.y = iv;
    tile2[c * 264 + row] = pr;
  }
  __syncthreads();
  const int lane = threadIdx.x & 63;
  const int q = threadIdx.x >> 6;
  const float4* H4 = (const float4*)(ws + WS_H);
  const int gs = 3 * g;
  float accs[3] = {0.f, 0.f, 0.f}, accn[3] = {0.f, 0.f, 0.f};
  for (int kk = 0; kk < 25; ++kk) {
    int k = __builtin_amdgcn_readfirstlane(q * 50 + kk * 2);  // taps k and k+1
    int rb = lane + 198 - k;      // LDS row of tap k+1 (tap k at rb+1)
#pragma unroll
    for (int s = 0; s < 3; ++s) {
      f32x2 v0 = tile2[s * 264 + rb];       // data multiplied by tap k+1
      f32x2 v1 = tile2[s * 264 + rb + 1];   // data multiplied by tap k
      float4 h0 = H4[k * 12 + gs + s];
      float4 h1 = H4[(k + 1) * 12 + gs + s];
      accs[s] += h0.x * v1.x + h0.y * v1.y + h1.x * v0.x + h1.y * v0.y;
      accn[s] += h0.z * v1.x + h0.w * v1.y + h1.z * v0.x + h1.w * v0.y;
    }
  }
  float* mr = red + (q * 64 + lane) * 7;
#pragma unroll
  for (int s = 0; s < 3; ++s) { mr[s] = accs[s]; mr[3 + s] = accn[s]; }
  __syncthreads();
  for (int p = threadIdx.x; p < 64 * 6; p += 256) {
    int row = p / 6, c = p - row * 6;
    if (t0 + row < TD) {
      float sum = red[row * 7 + c] + red[(64 + row) * 7 + c] +
                  red[(128 + row) * 7 + c] + red[(192 + row) * 7 + c];
      int ch = (c < 3) ? (3 * g + c) : (9 + 3 * g + c);
      ws[WS_SYN + (size_t)(t0 + row) * 24 + ch] = sum;
    }
  }
}

// ---------------- K45: one thread per t. C_den strictly lower-tri => nilpotent
// => bounded influence horizon; 13-step warm-up makes A[t-1] and A[t] exact.
// Warm-up loop has FIXED trip count (d=12..0, predicated) so the compiler can
// fully unroll and hoist/overlap the 39 L2 loads instead of serializing them.
__global__ void k45_out(
    const float* __restrict__ Cden, const float* __restrict__ Ws_sub,
    const float* __restrict__ Wns_sub, const float* __restrict__ Th_s,
    const float* __restrict__ Th_ns, const float* __restrict__ ws,
    float* __restrict__ out) {
  __shared__ float lout[64 * 35];
  const int t = blockIdx.x * 64 + threadIdx.x;
  float v[35];
#pragma unroll
  for (int m = 0; m < 35; ++m) v[m] = 0.f;
  if (t < TD) {
    const float* SYN = ws + WS_SYN;
    float dns[12][12];
#pragma unroll
    for (int i = 1; i < 12; ++i)
#pragma unroll
      for (int j = 0; j < i; ++j) dns[i][j] = Cden[i * 12 + j] * Wns_sub[j];
    float th[12];
#pragma unroll
    for (int i = 0; i < 12; ++i) th[i] = Th_ns[i];
    float ap[12], an[12];
#pragma unroll
    for (int i = 0; i < 12; ++i) { ap[i] = 0.f; an[i] = 0.f; }
#pragma unroll
    for (int d = 12; d >= 0; --d) {
      int tau = t - d;
      if (tau >= 0) {
        const float4* sr = (const float4*)(SYN + (size_t)tau * 24 + 12);
        float4 s0 = sr[0], s1 = sr[1], s2 = sr[2];
        float sn[12] = {s0.x, s0.y, s0.z, s0.w, s1.x, s1.y, s1.z, s1.w,
                        s2.x, s2.y, s2.z, s2.w};
#pragma unroll
        for (int i = 0; i < 12; ++i) {
          float x = sn[i] + th[i];
#pragma unroll
          for (int j = 0; j < i; ++j) x += dns[i][j] * ap[j];
          an[i] = sigf(x);
        }
        if (d > 0) {
#pragma unroll
          for (int i = 0; i < 12; ++i) ap[i] = an[i];
        }
      }
    }
    // an = A[t], ap = A[t-1] (zeros if t==0)
    float sns[12];
    {
      const float4* sr = (const float4*)(SYN + (size_t)t * 24);
      float4 s0 = sr[0], s1 = sr[1], s2 = sr[2];
      sns[0] = s0.x; sns[1] = s0.y; sns[2] = s0.z; sns[3] = s0.w;
      sns[4] = s1.x; sns[5] = s1.y; sns[6] = s1.z; sns[7] = s1.w;
      sns[8] = s2.x; sns[9] = s2.y; sns[10] = s2.z; sns[11] = s2.w;
    }
    float carry[12];
    carry[0] = (t > 0) ? Ws_sub[0] * sigf(SYN[(size_t)(t - 1) * 24] + Th_s[0]) : 0.f;
#pragma unroll
    for (int j = 1; j < 12; ++j) carry[j] = Ws_sub[j] * ap[j];
    float B[12];
#pragma unroll
    for (int i = 0; i < 12; ++i) {
      float x = sns[i] + Th_s[i];
#pragma unroll
      for (int j = 0; j < i; ++j) x += Cden[i * 12 + j] * carry[j];
      B[i] = sigf(x);
    }
    v[0] = B[0] * Ws_sub[0];
#pragma unroll
    for (int i = 1; i < 12; ++i) v[i] = an[i] * Ws_sub[i];
#pragma unroll
    for (int i = 0; i < 12; ++i) v[12 + i] = an[i] * Wns_sub[i];
#pragma unroll
    for (int i = 1; i < 12; ++i) v[23 + i] = B[i];
  }
#pragma unroll
  for (int m = 0; m < 35; ++m) lout[threadIdx.x * 35 + m] = v[m];
  __syncthreads();
  const int t0 = blockIdx.x * 64;
  int nrow = TD - t0; if (nrow > 64) nrow = 64;
  const int valid = nrow * 35;
  for (int p = threadIdx.x; p < valid; p += 64) out[(size_t)t0 * 35 + p] = lout[p];
}

extern "C" void kernel_launch(void* const* d_in, const int* in_sizes, int n_in,
                              void* d_out, int out_size, void* d_ws, size_t ws_size,
                              hipStream_t stream) {
  const float* Se = (const float*)d_in[0];
  const float* Si = (const float*)d_in[1];
  const float* Ce = (const float*)d_in[2];
  const float* Ci = (const float*)d_in[3];
  const float* Cden = (const float*)d_in[4];
  const float* Wsy_s = (const float*)d_in[5];
  const float* Wsy_ns = (const float*)d_in[6];
  const float* Del_s = (const float*)d_in[7];
  const float* Del_ns = (const float*)d_in[8];
  const float* Th_s = (const float*)d_in[9];
  const float* Th_ns = (const float*)d_in[10];
  const float* Ws_sub = (const float*)d_in[11];
  const float* Wns_sub = (const float*)d_in[12];
  // d_in[13..16] (hist/prop weights) multiply an identically-zero history buffer.
  float* ws = (float*)d_ws;
  float* out = (float*)d_out;

  k1_precomp<<<20, 256, 0, stream>>>(Ce, Ci, Wsy_s, Wsy_ns, Del_s, Del_ns, ws);
  k2_project<<<2500, 256, 0, stream>>>(Se, Si, ws);
  dim3 g3(313, 4);
  k3_conv<<<g3, 256, 0, stream>>>(ws);
  k45_out<<<313, 64, 0, stream>>>(Cden, Ws_sub, Wns_sub, Th_s, Th_ns, ws, out);
}

// Round 4
// 312.294 us; speedup vs baseline: 1.0044x; 1.0044x over previous
//
#include <hip/hip_runtime.h>

typedef unsigned int uint;
typedef unsigned long long u64;
typedef float f32x4 __attribute__((ext_vector_type(4)));
typedef float f32x2 __attribute__((ext_vector_type(2)));

#define TD 20000
// ws layout in float units:
//  H:      [200][12][4]  = 9600 floats  (FIR taps: {e_s, i_s, e_ns, i_ns} per (k,s))
//  SPREAD: 5000 uints, SoA uint4 arrays of 5-bit-field spread masks:
//          Ea[500] | Eb[500] | Ia[125] | Ib[125]  (uint4 units)
//  IN:     [20000][24]   (e counts in 0..11, i counts in 12..23)
//  SYN:    [20000][24]   (syn_s in 0..11, syn_ns in 12..23)
#define WS_H      0
#define WS_SPREAD 9600
#define WS_IN     14600
#define WS_SYN    494600

__device__ __forceinline__ float sigf(float x) { return 1.f / (1.f + __expf(-x)); }

// ---------------- K1: FIR kernels + spread connectivity masks (SoA) ----------------
__global__ __launch_bounds__(256) void k1_precomp(
    const float* __restrict__ Ce, const float* __restrict__ Ci,
    const float* __restrict__ Wsy_s, const float* __restrict__ Wsy_ns,
    const float* __restrict__ Del_s, const float* __restrict__ Del_ns,
    float* __restrict__ ws) {
  int p = blockIdx.x * 256 + threadIdx.x;
  if (p < 2400) {
    int k = p / 12, s = p - (p / 12) * 12;
    float o[4];
    for (int ch = 0; ch < 2; ++ch) {
      const float* W = ch ? Wsy_ns : Wsy_s;
      const float* D = ch ? Del_ns : Del_s;
      for (int c = 0; c < 2; ++c) {
        float ts = fmaxf((float)k - __expf(D[s * 2 + c]), 0.f);
        float v = 0.f;
        for (int b = 0; b < 3; ++b) {
          float tt = ts * __expf(-0.5f * (float)b);
          v += W[s * 6 + b * 2 + c] * tt * __expf(-tt);
        }
        o[ch * 2 + c] = v;
      }
    }
    float* H = ws + WS_H + (size_t)(k * 12 + s) * 4;
    H[0] = o[0]; H[1] = o[1]; H[2] = o[2]; H[3] = o[3];
  }
  int q = p - 2400;
  if (q >= 0 && q < 2500) {
    uint m = 0;
    if (q < 2000) {
      for (int s = 0; s < 12; ++s) m |= (Ce[s * 2000 + q] != 0.f ? (1u << s) : 0u);
    } else {
      int e = q - 2000;
      for (int s = 0; s < 12; ++s) m |= (Ci[s * 500 + e] != 0.f ? (1u << s) : 0u);
    }
    u64 sp = 0ull;
    for (int s = 0; s < 12; ++s) sp |= (u64)((m >> s) & 1u) << (5 * s);
    uint lo = (uint)sp, hi = (uint)(sp >> 32);
    uint* U = (uint*)(ws + WS_SPREAD);
    int base, idx;
    if (q < 2000) {
      int g4 = q >> 2, r = q & 3;
      base = (r < 2) ? 0 : 2000;          // Ea : Eb
      idx = g4 * 4 + 2 * (r & 1);
    } else {
      int e = q - 2000;
      int g4 = e >> 2, r = e & 3;
      base = (r < 2) ? 4000 : 4500;       // Ia : Ib
      idx = g4 * 4 + 2 * (r & 1);
    }
    U[base + idx] = lo;
    U[base + idx + 1] = hi;
  }
}

// ---------------- K2: IN = S @ C^T via spread-mask accumulation ----------------
// 2 time-rows per wave; masks read directly from global (L1-resident 20 KB,
// SoA layout -> 16B lane stride, fully coalesced, no LDS, no syncthreads).
// Memory-floor bound: 200 MB spike reads ~= 30 us.
__global__ __launch_bounds__(256) void k2_project(
    const float* __restrict__ Se, const float* __restrict__ Si,
    float* __restrict__ ws) {
  const int lane = threadIdx.x & 63;
  const int w = blockIdx.x * 4 + (threadIdx.x >> 6);  // row pair 0..9999
  const size_t t0 = (size_t)w * 2;
  const uint4* U4 = (const uint4*)(ws + WS_SPREAD);
  float* INb = ws + WS_IN;

  uint e0[12], e1[12];
#pragma unroll
  for (int s = 0; s < 12; ++s) { e0[s] = 0u; e1[s] = 0u; }
  u64 a0 = 0ull, a1 = 0ull;
  const f32x4* S0 = (const f32x4*)(Se + t0 * 2000);
  const f32x4* S1 = S0 + 500;
#pragma unroll
  for (int it = 0; it < 8; ++it) {
    int i4 = lane + it * 64;
    if (i4 < 500) {
      uint4 a = U4[i4];
      uint4 b = U4[500 + i4];
      u64 m0 = (u64)a.x | ((u64)a.y << 32);
      u64 m1 = (u64)a.z | ((u64)a.w << 32);
      u64 m2 = (u64)b.x | ((u64)b.y << 32);
      u64 m3 = (u64)b.z | ((u64)b.w << 32);
      f32x4 v0 = __builtin_nontemporal_load(&S0[i4]);
      f32x4 v1 = __builtin_nontemporal_load(&S1[i4]);
      a0 += (v0.x != 0.f ? m0 : 0ull); a1 += (v1.x != 0.f ? m0 : 0ull);
      a0 += (v0.y != 0.f ? m1 : 0ull); a1 += (v1.y != 0.f ? m1 : 0ull);
      a0 += (v0.z != 0.f ? m2 : 0ull); a1 += (v1.z != 0.f ? m2 : 0ull);
      a0 += (v0.w != 0.f ? m3 : 0ull); a1 += (v1.w != 0.f ? m3 : 0ull);
    }
    if (it == 3) {
#pragma unroll
      for (int s = 0; s < 12; ++s) {
        e0[s] += (uint)(a0 >> (5 * s)) & 31u;
        e1[s] += (uint)(a1 >> (5 * s)) & 31u;
      }
      a0 = 0ull; a1 = 0ull;
    }
  }
#pragma unroll
  for (int s = 0; s < 12; ++s) {
    e0[s] += (uint)(a0 >> (5 * s)) & 31u;
    e1[s] += (uint)(a1 >> (5 * s)) & 31u;
  }
  // ----- I channel (max 8 per field, no flush needed) -----
  u64 ai0 = 0ull, ai1 = 0ull;
  const f32x4* T0 = (const f32x4*)(Si + t0 * 500);
  const f32x4* T1 = T0 + 125;
#pragma unroll
  for (int it = 0; it < 2; ++it) {
    int i4 = lane + it * 64;
    if (i4 < 125) {
      uint4 a = U4[1000 + i4];
      uint4 b = U4[1125 + i4];
      u64 m0 = (u64)a.x | ((u64)a.y << 32);
      u64 m1 = (u64)a.z | ((u64)a.w << 32);
      u64 m2 = (u64)b.x | ((u64)b.y << 32);
      u64 m3 = (u64)b.z | ((u64)b.w << 32);
      f32x4 v0 = __builtin_nontemporal_load(&T0[i4]);
      f32x4 v1 = __builtin_nontemporal_load(&T1[i4]);
      ai0 += (v0.x != 0.f ? m0 : 0ull); ai1 += (v1.x != 0.f ? m0 : 0ull);
      ai0 += (v0.y != 0.f ? m1 : 0ull); ai1 += (v1.y != 0.f ? m1 : 0ull);
      ai0 += (v0.z != 0.f ? m2 : 0ull); ai1 += (v1.z != 0.f ? m2 : 0ull);
      ai0 += (v0.w != 0.f ? m3 : 0ull); ai1 += (v1.w != 0.f ? m3 : 0ull);
    }
  }
  uint p0[12], p1[12];
#pragma unroll
  for (int s = 0; s < 12; ++s) {
    p0[s] = e0[s] | (((uint)(ai0 >> (5 * s)) & 31u) << 16);
    p1[s] = e1[s] | (((uint)(ai1 >> (5 * s)) & 31u) << 16);
  }
#pragma unroll
  for (int s = 0; s < 12; ++s) {
    uint v = p0[s];
    v += __shfl_xor(v, 32, 64); v += __shfl_xor(v, 16, 64);
    v += __shfl_xor(v, 8, 64);  v += __shfl_xor(v, 4, 64);
    v += __shfl_xor(v, 2, 64);  v += __shfl_xor(v, 1, 64);
    p0[s] = v;
    uint u = p1[s];
    u += __shfl_xor(u, 32, 64); u += __shfl_xor(u, 16, 64);
    u += __shfl_xor(u, 8, 64);  u += __shfl_xor(u, 4, 64);
    u += __shfl_xor(u, 2, 64);  u += __shfl_xor(u, 1, 64);
    p1[s] = u;
  }
  if (lane == 0) {
    float4* o = (float4*)(INb + t0 * 24);
    o[0] = make_float4((float)(p0[0] & 0xffffu), (float)(p0[1] & 0xffffu),
                       (float)(p0[2] & 0xffffu), (float)(p0[3] & 0xffffu));
    o[1] = make_float4((float)(p0[4] & 0xffffu), (float)(p0[5] & 0xffffu),
                       (float)(p0[6] & 0xffffu), (float)(p0[7] & 0xffffu));
    o[2] = make_float4((float)(p0[8] & 0xffffu), (float)(p0[9] & 0xffffu),
                       (float)(p0[10] & 0xffffu), (float)(p0[11] & 0xffffu));
    o[3] = make_float4((float)(p0[0] >> 16), (float)(p0[1] >> 16),
                       (float)(p0[2] >> 16), (float)(p0[3] >> 16));
    o[4] = make_float4((float)(p0[4] >> 16), (float)(p0[5] >> 16),
                       (float)(p0[6] >> 16), (float)(p0[7] >> 16));
    o[5] = make_float4((float)(p0[8] >> 16), (float)(p0[9] >> 16),
                       (float)(p0[10] >> 16), (float)(p0[11] >> 16));
  }
  if (lane == 1) {
    float4* o = (float4*)(INb + (t0 + 1) * 24);
    o[0] = make_float4((float)(p1[0] & 0xffffu), (float)(p1[1] & 0xffffu),
                       (float)(p1[2] & 0xffffu), (float)(p1[3] & 0xffffu));
    o[1] = make_float4((float)(p1[4] & 0xffffu), (float)(p1[5] & 0xffffu),
                       (float)(p1[6] & 0xffffu), (float)(p1[7] & 0xffffu));
    o[2] = make_float4((float)(p1[8] & 0xffffu), (float)(p1[9] & 0xffffu),
                       (float)(p1[10] & 0xffffu), (float)(p1[11] & 0xffffu));
    o[3] = make_float4((float)(p1[0] >> 16), (float)(p1[1] >> 16),
                       (float)(p1[2] >> 16), (float)(p1[3] >> 16));
    o[4] = make_float4((float)(p1[4] >> 16), (float)(p1[5] >> 16),
                       (float)(p1[6] >> 16), (float)(p1[7] >> 16));
    o[5] = make_float4((float)(p1[8] >> 16), (float)(p1[9] >> 16),
                       (float)(p1[10] >> 16), (float)(p1[11] >> 16));
  }
}

// ---------------- K3: causal FIR, K=200, s-group split across blockIdx.y ----------------
// block = 64 t's x 3 subunits (both channels); 4 waves split the 200 taps.
// LDS tile interleaved as float2 {e,i} per (s,row): one tap's pair = a single
// 8B-aligned ds_read_b64 -> DS issues halved vs b32 pairs. red[] row stride 7
// (gcd(7,32)=1, no conflict). Tap index wave-uniform via readfirstlane -> s_load.
__global__ __launch_bounds__(256) void k3_conv(float* __restrict__ ws) {
  __shared__ f32x2 tile2[3 * 264];
  __shared__ float red[4 * 64 * 7];
  const int g = blockIdx.y;        // subunit group: s in [3g, 3g+3)
  const int t0 = blockIdx.x * 64;
  const float* INb = ws + WS_IN;
  for (int p = threadIdx.x; p < 263 * 3; p += 256) {
    int row = p / 3, c = p - row * 3;
    int gt = t0 - 199 + row;
    float ev = 0.f, iv = 0.f;
    if (gt >= 0 && gt < TD) {
      ev = INb[(size_t)gt * 24 + 3 * g + c];
      iv = INb[(size_t)gt * 24 + 12 + 3 * g + c];
    }
    f32x2 pr; pr.x = ev; pr.y = iv;
    tile2[c * 264 + row] = pr;
  }
  __syncthreads();
  const int lane = threadIdx.x & 63;
  const int q = threadIdx.x >> 6;
  const float4* H4 = (const float4*)(ws + WS_H);
  const int gs = 3 * g;
  float accs[3] = {0.f, 0.f, 0.f}, accn[3] = {0.f, 0.f, 0.f};
  for (int kk = 0; kk < 25; ++kk) {
    int k = __builtin_amdgcn_readfirstlane(q * 50 + kk * 2);  // taps k and k+1
    int rb = lane + 198 - k;      // LDS row of tap k+1 (tap k at rb+1)
#pragma unroll
    for (int s = 0; s < 3; ++s) {
      f32x2 v0 = tile2[s * 264 + rb];       // data multiplied by tap k+1
      f32x2 v1 = tile2[s * 264 + rb + 1];   // data multiplied by tap k
      float4 h0 = H4[k * 12 + gs + s];
      float4 h1 = H4[(k + 1) * 12 + gs + s];
      accs[s] += h0.x * v1.x + h0.y * v1.y + h1.x * v0.x + h1.y * v0.y;
      accn[s] += h0.z * v1.x + h0.w * v1.y + h1.z * v0.x + h1.w * v0.y;
    }
  }
  float* mr = red + (q * 64 + lane) * 7;
#pragma unroll
  for (int s = 0; s < 3; ++s) { mr[s] = accs[s]; mr[3 + s] = accn[s]; }
  __syncthreads();
  for (int p = threadIdx.x; p < 64 * 6; p += 256) {
    int row = p / 6, c = p - row * 6;
    if (t0 + row < TD) {
      float sum = red[row * 7 + c] + red[(64 + row) * 7 + c] +
                  red[(128 + row) * 7 + c] + red[(192 + row) * 7 + c];
      int ch = (c < 3) ? (3 * g + c) : (9 + 3 * g + c);
      ws[WS_SYN + (size_t)(t0 + row) * 24 + ch] = sum;
    }
  }
}

// ---------------- K45: one thread per t. C_den strictly lower-tri => nilpotent
// => bounded influence horizon; 13-step warm-up makes A[t-1] and A[t] exact.
// Runtime-trip warm-up (NOT unrolled): full unroll hoists ~39 float4 loads and
// blows past the VGPR budget -> scratch spills (round-3 regression, +8 us).
__global__ void k45_out(
    const float* __restrict__ Cden, const float* __restrict__ Ws_sub,
    const float* __restrict__ Wns_sub, const float* __restrict__ Th_s,
    const float* __restrict__ Th_ns, const float* __restrict__ ws,
    float* __restrict__ out) {
  __shared__ float lout[64 * 35];
  const int t = blockIdx.x * 64 + threadIdx.x;
  float v[35];
#pragma unroll
  for (int m = 0; m < 35; ++m) v[m] = 0.f;
  if (t < TD) {
    const float* SYN = ws + WS_SYN;
    float dns[12][12];
#pragma unroll
    for (int i = 1; i < 12; ++i)
#pragma unroll
      for (int j = 0; j < i; ++j) dns[i][j] = Cden[i * 12 + j] * Wns_sub[j];
    float th[12];
#pragma unroll
    for (int i = 0; i < 12; ++i) th[i] = Th_ns[i];
    float ap[12], an[12];
#pragma unroll
    for (int i = 0; i < 12; ++i) { ap[i] = 0.f; an[i] = 0.f; }
    int start = t - 12; if (start < 0) start = 0;
    for (int tau = start; tau <= t; ++tau) {
      const float4* sr = (const float4*)(SYN + (size_t)tau * 24 + 12);
      float4 s0 = sr[0], s1 = sr[1], s2 = sr[2];
      float sn[12] = {s0.x, s0.y, s0.z, s0.w, s1.x, s1.y, s1.z, s1.w,
                      s2.x, s2.y, s2.z, s2.w};
#pragma unroll
      for (int i = 0; i < 12; ++i) {
        float x = sn[i] + th[i];
#pragma unroll
        for (int j = 0; j < i; ++j) x += dns[i][j] * ap[j];
        an[i] = sigf(x);
      }
      if (tau < t) {
#pragma unroll
        for (int i = 0; i < 12; ++i) ap[i] = an[i];
      }
    }
    // an = A[t], ap = A[t-1] (zeros if t==0)
    float sns[12];
    {
      const float4* sr = (const float4*)(SYN + (size_t)t * 24);
      float4 s0 = sr[0], s1 = sr[1], s2 = sr[2];
      sns[0] = s0.x; sns[1] = s0.y; sns[2] = s0.z; sns[3] = s0.w;
      sns[4] = s1.x; sns[5] = s1.y; sns[6] = s1.z; sns[7] = s1.w;
      sns[8] = s2.x; sns[9] = s2.y; sns[10] = s2.z; sns[11] = s2.w;
    }
    float carry[12];
    carry[0] = (t > 0) ? Ws_sub[0] * sigf(SYN[(size_t)(t - 1) * 24] + Th_s[0]) : 0.f;
#pragma unroll
    for (int j = 1; j < 12; ++j) carry[j] = Ws_sub[j] * ap[j];
    float B[12];
#pragma unroll
    for (int i = 0; i < 12; ++i) {
      float x = sns[i] + Th_s[i];
#pragma unroll
      for (int j = 0; j < i; ++j) x += Cden[i * 12 + j] * carry[j];
      B[i] = sigf(x);
    }
    v[0] = B[0] * Ws_sub[0];
#pragma unroll
    for (int i = 1; i < 12; ++i) v[i] = an[i] * Ws_sub[i];
#pragma unroll
    for (int i = 0; i < 12; ++i) v[12 + i] = an[i] * Wns_sub[i];
#pragma unroll
    for (int i = 1; i < 12; ++i) v[23 + i] = B[i];
  }
#pragma unroll
  for (int m = 0; m < 35; ++m) lout[threadIdx.x * 35 + m] = v[m];
  __syncthreads();
  const int t0 = blockIdx.x * 64;
  int nrow = TD - t0; if (nrow > 64) nrow = 64;
  const int valid = nrow * 35;
  for (int p = threadIdx.x; p < valid; p += 64) out[(size_t)t0 * 35 + p] = lout[p];
}

extern "C" void kernel_launch(void* const* d_in, const int* in_sizes, int n_in,
                              void* d_out, int out_size, void* d_ws, size_t ws_size,
                              hipStream_t stream) {
  const float* Se = (const float*)d_in[0];
  const float* Si = (const float*)d_in[1];
  const float* Ce = (const float*)d_in[2];
  const float* Ci = (const float*)d_in[3];
  const float* Cden = (const float*)d_in[4];
  const float* Wsy_s = (const float*)d_in[5];
  const float* Wsy_ns = (const float*)d_in[6];
  const float* Del_s = (const float*)d_in[7];
  const float* Del_ns = (const float*)d_in[8];
  const float* Th_s = (const float*)d_in[9];
  const float* Th_ns = (const float*)d_in[10];
  const float* Ws_sub = (const float*)d_in[11];
  const float* Wns_sub = (const float*)d_in[12];
  // d_in[13..16] (hist/prop weights) multiply an identically-zero history buffer.
  float* ws = (float*)d_ws;
  float* out = (float*)d_out;

  k1_precomp<<<20, 256, 0, stream>>>(Ce, Ci, Wsy_s, Wsy_ns, Del_s, Del_ns, ws);
  k2_project<<<2500, 256, 0, stream>>>(Se, Si, ws);
  dim3 g3(313, 4);
  k3_conv<<<g3, 256, 0, stream>>>(ws);
  k45_out<<<313, 64, 0, stream>>>(Cden, Ws_sub, Wns_sub, Th_s, Th_ns, ws, out);
}

// Round 5
// 302.346 us; speedup vs baseline: 1.0375x; 1.0329x over previous
//
#include <hip/hip_runtime.h>

typedef unsigned int uint;
typedef unsigned long long u64;
typedef float f32x4 __attribute__((ext_vector_type(4)));

#define TD 20000
// ws layout in float units:
//  H:      [200][12][4]  = 9600 floats  (FIR taps: {e_s, i_s, e_ns, i_ns} per (k,s))
//  SPREAD: 5000 uints, SoA uint4 arrays of 5-bit-field spread masks:
//          Ea[500] | Eb[500] | Ia[125] | Ib[125]  (uint4 units)
//  IN:     [20000][24]   (e counts in 0..11, i counts in 12..23)
//  SYN:    [20000][24]   (syn_s in 0..11, syn_ns in 12..23)
#define WS_H      0
#define WS_SPREAD 9600
#define WS_IN     14600
#define WS_SYN    494600

__device__ __forceinline__ float sigf(float x) { return 1.f / (1.f + __expf(-x)); }

// ---------------- K1: FIR kernels + spread connectivity masks (SoA) ----------------
__global__ __launch_bounds__(256) void k1_precomp(
    const float* __restrict__ Ce, const float* __restrict__ Ci,
    const float* __restrict__ Wsy_s, const float* __restrict__ Wsy_ns,
    const float* __restrict__ Del_s, const float* __restrict__ Del_ns,
    float* __restrict__ ws) {
  int p = blockIdx.x * 256 + threadIdx.x;
  if (p < 2400) {
    int k = p / 12, s = p - (p / 12) * 12;
    float o[4];
    for (int ch = 0; ch < 2; ++ch) {
      const float* W = ch ? Wsy_ns : Wsy_s;
      const float* D = ch ? Del_ns : Del_s;
      for (int c = 0; c < 2; ++c) {
        float ts = fmaxf((float)k - __expf(D[s * 2 + c]), 0.f);
        float v = 0.f;
        for (int b = 0; b < 3; ++b) {
          float tt = ts * __expf(-0.5f * (float)b);
          v += W[s * 6 + b * 2 + c] * tt * __expf(-tt);
        }
        o[ch * 2 + c] = v;
      }
    }
    float* H = ws + WS_H + (size_t)(k * 12 + s) * 4;
    H[0] = o[0]; H[1] = o[1]; H[2] = o[2]; H[3] = o[3];
  }
  int q = p - 2400;
  if (q >= 0 && q < 2500) {
    uint m = 0;
    if (q < 2000) {
      for (int s = 0; s < 12; ++s) m |= (Ce[s * 2000 + q] != 0.f ? (1u << s) : 0u);
    } else {
      int e = q - 2000;
      for (int s = 0; s < 12; ++s) m |= (Ci[s * 500 + e] != 0.f ? (1u << s) : 0u);
    }
    u64 sp = 0ull;
    for (int s = 0; s < 12; ++s) sp |= (u64)((m >> s) & 1u) << (5 * s);
    uint lo = (uint)sp, hi = (uint)(sp >> 32);
    uint* U = (uint*)(ws + WS_SPREAD);
    int base, idx;
    if (q < 2000) {
      int g4 = q >> 2, r = q & 3;
      base = (r < 2) ? 0 : 2000;          // Ea : Eb
      idx = g4 * 4 + 2 * (r & 1);
    } else {
      int e = q - 2000;
      int g4 = e >> 2, r = e & 3;
      base = (r < 2) ? 4000 : 4500;       // Ia : Ib
      idx = g4 * 4 + 2 * (r & 1);
    }
    U[base + idx] = lo;
    U[base + idx + 1] = hi;
  }
}

// ---------------- K2: IN = S @ C^T via spread-mask accumulation ----------------
// 2 time-rows per wave; masks read directly from global (L1-resident 20 KB,
// SoA layout -> 16B lane stride, fully coalesced, no LDS, no syncthreads).
// Memory-floor bound: 200 MB spike reads ~= 30 us.
__global__ __launch_bounds__(256) void k2_project(
    const float* __restrict__ Se, const float* __restrict__ Si,
    float* __restrict__ ws) {
  const int lane = threadIdx.x & 63;
  const int w = blockIdx.x * 4 + (threadIdx.x >> 6);  // row pair 0..9999
  const size_t t0 = (size_t)w * 2;
  const uint4* U4 = (const uint4*)(ws + WS_SPREAD);
  float* INb = ws + WS_IN;

  uint e0[12], e1[12];
#pragma unroll
  for (int s = 0; s < 12; ++s) { e0[s] = 0u; e1[s] = 0u; }
  u64 a0 = 0ull, a1 = 0ull;
  const f32x4* S0 = (const f32x4*)(Se + t0 * 2000);
  const f32x4* S1 = S0 + 500;
#pragma unroll
  for (int it = 0; it < 8; ++it) {
    int i4 = lane + it * 64;
    if (i4 < 500) {
      uint4 a = U4[i4];
      uint4 b = U4[500 + i4];
      u64 m0 = (u64)a.x | ((u64)a.y << 32);
      u64 m1 = (u64)a.z | ((u64)a.w << 32);
      u64 m2 = (u64)b.x | ((u64)b.y << 32);
      u64 m3 = (u64)b.z | ((u64)b.w << 32);
      f32x4 v0 = __builtin_nontemporal_load(&S0[i4]);
      f32x4 v1 = __builtin_nontemporal_load(&S1[i4]);
      a0 += (v0.x != 0.f ? m0 : 0ull); a1 += (v1.x != 0.f ? m0 : 0ull);
      a0 += (v0.y != 0.f ? m1 : 0ull); a1 += (v1.y != 0.f ? m1 : 0ull);
      a0 += (v0.z != 0.f ? m2 : 0ull); a1 += (v1.z != 0.f ? m2 : 0ull);
      a0 += (v0.w != 0.f ? m3 : 0ull); a1 += (v1.w != 0.f ? m3 : 0ull);
    }
    if (it == 3) {
#pragma unroll
      for (int s = 0; s < 12; ++s) {
        e0[s] += (uint)(a0 >> (5 * s)) & 31u;
        e1[s] += (uint)(a1 >> (5 * s)) & 31u;
      }
      a0 = 0ull; a1 = 0ull;
    }
  }
#pragma unroll
  for (int s = 0; s < 12; ++s) {
    e0[s] += (uint)(a0 >> (5 * s)) & 31u;
    e1[s] += (uint)(a1 >> (5 * s)) & 31u;
  }
  // ----- I channel (max 8 per field, no flush needed) -----
  u64 ai0 = 0ull, ai1 = 0ull;
  const f32x4* T0 = (const f32x4*)(Si + t0 * 500);
  const f32x4* T1 = T0 + 125;
#pragma unroll
  for (int it = 0; it < 2; ++it) {
    int i4 = lane + it * 64;
    if (i4 < 125) {
      uint4 a = U4[1000 + i4];
      uint4 b = U4[1125 + i4];
      u64 m0 = (u64)a.x | ((u64)a.y << 32);
      u64 m1 = (u64)a.z | ((u64)a.w << 32);
      u64 m2 = (u64)b.x | ((u64)b.y << 32);
      u64 m3 = (u64)b.z | ((u64)b.w << 32);
      f32x4 v0 = __builtin_nontemporal_load(&T0[i4]);
      f32x4 v1 = __builtin_nontemporal_load(&T1[i4]);
      ai0 += (v0.x != 0.f ? m0 : 0ull); ai1 += (v1.x != 0.f ? m0 : 0ull);
      ai0 += (v0.y != 0.f ? m1 : 0ull); ai1 += (v1.y != 0.f ? m1 : 0ull);
      ai0 += (v0.z != 0.f ? m2 : 0ull); ai1 += (v1.z != 0.f ? m2 : 0ull);
      ai0 += (v0.w != 0.f ? m3 : 0ull); ai1 += (v1.w != 0.f ? m3 : 0ull);
    }
  }
  uint p0[12], p1[12];
#pragma unroll
  for (int s = 0; s < 12; ++s) {
    p0[s] = e0[s] | (((uint)(ai0 >> (5 * s)) & 31u) << 16);
    p1[s] = e1[s] | (((uint)(ai1 >> (5 * s)) & 31u) << 16);
  }
#pragma unroll
  for (int s = 0; s < 12; ++s) {
    uint v = p0[s];
    v += __shfl_xor(v, 32, 64); v += __shfl_xor(v, 16, 64);
    v += __shfl_xor(v, 8, 64);  v += __shfl_xor(v, 4, 64);
    v += __shfl_xor(v, 2, 64);  v += __shfl_xor(v, 1, 64);
    p0[s] = v;
    uint u = p1[s];
    u += __shfl_xor(u, 32, 64); u += __shfl_xor(u, 16, 64);
    u += __shfl_xor(u, 8, 64);  u += __shfl_xor(u, 4, 64);
    u += __shfl_xor(u, 2, 64);  u += __shfl_xor(u, 1, 64);
    p1[s] = u;
  }
  if (lane == 0) {
    float4* o = (float4*)(INb + t0 * 24);
    o[0] = make_float4((float)(p0[0] & 0xffffu), (float)(p0[1] & 0xffffu),
                       (float)(p0[2] & 0xffffu), (float)(p0[3] & 0xffffu));
    o[1] = make_float4((float)(p0[4] & 0xffffu), (float)(p0[5] & 0xffffu),
                       (float)(p0[6] & 0xffffu), (float)(p0[7] & 0xffffu));
    o[2] = make_float4((float)(p0[8] & 0xffffu), (float)(p0[9] & 0xffffu),
                       (float)(p0[10] & 0xffffu), (float)(p0[11] & 0xffffu));
    o[3] = make_float4((float)(p0[0] >> 16), (float)(p0[1] >> 16),
                       (float)(p0[2] >> 16), (float)(p0[3] >> 16));
    o[4] = make_float4((float)(p0[4] >> 16), (float)(p0[5] >> 16),
                       (float)(p0[6] >> 16), (float)(p0[7] >> 16));
    o[5] = make_float4((float)(p0[8] >> 16), (float)(p0[9] >> 16),
                       (float)(p0[10] >> 16), (float)(p0[11] >> 16));
  }
  if (lane == 1) {
    float4* o = (float4*)(INb + (t0 + 1) * 24);
    o[0] = make_float4((float)(p1[0] & 0xffffu), (float)(p1[1] & 0xffffu),
                       (float)(p1[2] & 0xffffu), (float)(p1[3] & 0xffffu));
    o[1] = make_float4((float)(p1[4] & 0xffffu), (float)(p1[5] & 0xffffu),
                       (float)(p1[6] & 0xffffu), (float)(p1[7] & 0xffffu));
    o[2] = make_float4((float)(p1[8] & 0xffffu), (float)(p1[9] & 0xffffu),
                       (float)(p1[10] & 0xffffu), (float)(p1[11] & 0xffffu));
    o[3] = make_float4((float)(p1[0] >> 16), (float)(p1[1] >> 16),
                       (float)(p1[2] >> 16), (float)(p1[3] >> 16));
    o[4] = make_float4((float)(p1[4] >> 16), (float)(p1[5] >> 16),
                       (float)(p1[6] >> 16), (float)(p1[7] >> 16));
    o[5] = make_float4((float)(p1[8] >> 16), (float)(p1[9] >> 16),
                       (float)(p1[10] >> 16), (float)(p1[11] >> 16));
  }
}

// ---------------- K3: causal FIR, K=200, s-group split across blockIdx.y ----------------
// block = 64 t's x 3 subunits (both channels); 4 waves split the 200 taps.
// red[] row stride 7 (gcd(7,32)=1 -> conflict-free).
// Tap index forced wave-uniform via readfirstlane so tap loads go scalar (s_load).
// NOTE: b32 tile reads, NOT b64-pairs — LDS here is bandwidth-limited (same
// bytes either way) and the f32x2 variant's tile fill regressed (round 3/4).
__global__ __launch_bounds__(256) void k3_conv(float* __restrict__ ws) {
  __shared__ float tile[6 * 264];
  __shared__ float red[4 * 64 * 7];
  const int g = blockIdx.y;        // subunit group: s in [3g, 3g+3)
  const int t0 = blockIdx.x * 64;
  const float* INb = ws + WS_IN;
  for (int p = threadIdx.x; p < 263 * 6; p += 256) {
    int row = p / 6, c = p - row * 6;
    int ch = (c < 3) ? (3 * g + c) : (9 + 3 * g + c);  // e: 3g+c ; i: 12+3g+(c-3)
    int gt = t0 - 199 + row;
    tile[c * 264 + row] = (gt >= 0 && gt < TD) ? INb[(size_t)gt * 24 + ch] : 0.f;
  }
  __syncthreads();
  const int lane = threadIdx.x & 63;
  const int q = threadIdx.x >> 6;
  const float4* H4 = (const float4*)(ws + WS_H);
  const int gs = 3 * g;
  float accs[3] = {0.f, 0.f, 0.f}, accn[3] = {0.f, 0.f, 0.f};
  for (int kk = 0; kk < 25; ++kk) {
    int k = __builtin_amdgcn_readfirstlane(q * 50 + kk * 2);  // taps k and k+1
    int rb = lane + 198 - k;      // LDS row of tap k+1 (tap k at rb+1)
#pragma unroll
    for (int s = 0; s < 3; ++s) {
      float ve0 = tile[s * 264 + rb];
      float ve1 = tile[s * 264 + rb + 1];
      float vi0 = tile[(3 + s) * 264 + rb];
      float vi1 = tile[(3 + s) * 264 + rb + 1];
      float4 h0 = H4[k * 12 + gs + s];
      float4 h1 = H4[(k + 1) * 12 + gs + s];
      accs[s] += h0.x * ve1 + h0.y * vi1 + h1.x * ve0 + h1.y * vi0;
      accn[s] += h0.z * ve1 + h0.w * vi1 + h1.z * ve0 + h1.w * vi0;
    }
  }
  float* mr = red + (q * 64 + lane) * 7;
#pragma unroll
  for (int s = 0; s < 3; ++s) { mr[s] = accs[s]; mr[3 + s] = accn[s]; }
  __syncthreads();
  for (int p = threadIdx.x; p < 64 * 6; p += 256) {
    int row = p / 6, c = p - row * 6;
    if (t0 + row < TD) {
      float sum = red[row * 7 + c] + red[(64 + row) * 7 + c] +
                  red[(128 + row) * 7 + c] + red[(192 + row) * 7 + c];
      int ch = (c < 3) ? (3 * g + c) : (9 + 3 * g + c);
      ws[WS_SYN + (size_t)(t0 + row) * 24 + ch] = sum;
    }
  }
}

// ---------------- K45: one thread per t. C_den strictly lower-tri => nilpotent
// => bounded influence horizon; 13-step warm-up makes A[t-1] and A[t] exact.
// Runtime-trip warm-up (NOT unrolled): full unroll hoists ~39 float4 loads and
// spills (round-3 test).
__global__ void k45_out(
    const float* __restrict__ Cden, const float* __restrict__ Ws_sub,
    const float* __restrict__ Wns_sub, const float* __restrict__ Th_s,
    const float* __restrict__ Th_ns, const float* __restrict__ ws,
    float* __restrict__ out) {
  __shared__ float lout[64 * 35];
  const int t = blockIdx.x * 64 + threadIdx.x;
  float v[35];
#pragma unroll
  for (int m = 0; m < 35; ++m) v[m] = 0.f;
  if (t < TD) {
    const float* SYN = ws + WS_SYN;
    float dns[12][12];
#pragma unroll
    for (int i = 1; i < 12; ++i)
#pragma unroll
      for (int j = 0; j < i; ++j) dns[i][j] = Cden[i * 12 + j] * Wns_sub[j];
    float th[12];
#pragma unroll
    for (int i = 0; i < 12; ++i) th[i] = Th_ns[i];
    float ap[12], an[12];
#pragma unroll
    for (int i = 0; i < 12; ++i) { ap[i] = 0.f; an[i] = 0.f; }
    int start = t - 12; if (start < 0) start = 0;
    for (int tau = start; tau <= t; ++tau) {
      const float4* sr = (const float4*)(SYN + (size_t)tau * 24 + 12);
      float4 s0 = sr[0], s1 = sr[1], s2 = sr[2];
      float sn[12] = {s0.x, s0.y, s0.z, s0.w, s1.x, s1.y, s1.z, s1.w,
                      s2.x, s2.y, s2.z, s2.w};
#pragma unroll
      for (int i = 0; i < 12; ++i) {
        float x = sn[i] + th[i];
#pragma unroll
        for (int j = 0; j < i; ++j) x += dns[i][j] * ap[j];
        an[i] = sigf(x);
      }
      if (tau < t) {
#pragma unroll
        for (int i = 0; i < 12; ++i) ap[i] = an[i];
      }
    }
    // an = A[t], ap = A[t-1] (zeros if t==0)
    float sns[12];
    {
      const float4* sr = (const float4*)(SYN + (size_t)t * 24);
      float4 s0 = sr[0], s1 = sr[1], s2 = sr[2];
      sns[0] = s0.x; sns[1] = s0.y; sns[2] = s0.z; sns[3] = s0.w;
      sns[4] = s1.x; sns[5] = s1.y; sns[6] = s1.z; sns[7] = s1.w;
      sns[8] = s2.x; sns[9] = s2.y; sns[10] = s2.z; sns[11] = s2.w;
    }
    float carry[12];
    carry[0] = (t > 0) ? Ws_sub[0] * sigf(SYN[(size_t)(t - 1) * 24] + Th_s[0]) : 0.f;
#pragma unroll
    for (int j = 1; j < 12; ++j) carry[j] = Ws_sub[j] * ap[j];
    float B[12];
#pragma unroll
    for (int i = 0; i < 12; ++i) {
      float x = sns[i] + Th_s[i];
#pragma unroll
      for (int j = 0; j < i; ++j) x += Cden[i * 12 + j] * carry[j];
      B[i] = sigf(x);
    }
    v[0] = B[0] * Ws_sub[0];
#pragma unroll
    for (int i = 1; i < 12; ++i) v[i] = an[i] * Ws_sub[i];
#pragma unroll
    for (int i = 0; i < 12; ++i) v[12 + i] = an[i] * Wns_sub[i];
#pragma unroll
    for (int i = 1; i < 12; ++i) v[23 + i] = B[i];
  }
#pragma unroll
  for (int m = 0; m < 35; ++m) lout[threadIdx.x * 35 + m] = v[m];
  __syncthreads();
  const int t0 = blockIdx.x * 64;
  int nrow = TD - t0; if (nrow > 64) nrow = 64;
  const int valid = nrow * 35;
  for (int p = threadIdx.x; p < valid; p += 64) out[(size_t)t0 * 35 + p] = lout[p];
}

extern "C" void kernel_launch(void* const* d_in, const int* in_sizes, int n_in,
                              void* d_out, int out_size, void* d_ws, size_t ws_size,
                              hipStream_t stream) {
  const float* Se = (const float*)d_in[0];
  const float* Si = (const float*)d_in[1];
  const float* Ce = (const float*)d_in[2];
  const float* Ci = (const float*)d_in[3];
  const float* Cden = (const float*)d_in[4];
  const float* Wsy_s = (const float*)d_in[5];
  const float* Wsy_ns = (const float*)d_in[6];
  const float* Del_s = (const float*)d_in[7];
  const float* Del_ns = (const float*)d_in[8];
  const float* Th_s = (const float*)d_in[9];
  const float* Th_ns = (const float*)d_in[10];
  const float* Ws_sub = (const float*)d_in[11];
  const float* Wns_sub = (const float*)d_in[12];
  // d_in[13..16] (hist/prop weights) multiply an identically-zero history buffer.
  float* ws = (float*)d_ws;
  float* out = (float*)d_out;

  k1_precomp<<<20, 256, 0, stream>>>(Ce, Ci, Wsy_s, Wsy_ns, Del_s, Del_ns, ws);
  k2_project<<<2500, 256, 0, stream>>>(Se, Si, ws);
  dim3 g3(313, 4);
  k3_conv<<<g3, 256, 0, stream>>>(ws);
  k45_out<<<313, 64, 0, stream>>>(Cden, Ws_sub, Wns_sub, Th_s, Th_ns, ws, out);
}